// Round 8
// baseline (616.684 us; speedup 1.0000x reference)
//
#include <hip/hip_runtime.h>
#include <hip/hip_bf16.h>
#include <cstdint>

// Problem constants: B=8, L=4096, D=768, Y=2048
#define BB 8
#define LL 4096
#define DD 768
#define YY 2048

typedef unsigned short u16;
typedef __bf16 bf16x8 __attribute__((ext_vector_type(8)));
typedef __bf16 bf16x2 __attribute__((ext_vector_type(2)));
typedef float f32x4 __attribute__((ext_vector_type(4)));

__device__ __forceinline__ u16 f2bf(float f) {
    uint32_t u = __float_as_uint(f);
    u += 0x7fffu + ((u >> 16) & 1u);   // RNE
    return (u16)(u >> 16);
}

__device__ __forceinline__ uint32_t pkbf(float a, float b) {
#if __has_builtin(__builtin_amdgcn_cvt_pk_bf16_f32)
    bf16x2 p = __builtin_amdgcn_cvt_pk_bf16_f32(a, b);
    return __builtin_bit_cast(uint32_t, p);
#else
    return (uint32_t)f2bf(a) | ((uint32_t)f2bf(b) << 16);
#endif
}

#define GLL(src, dst) \
    __builtin_amdgcn_global_load_lds((const __attribute__((address_space(1))) unsigned int*)(src), \
                                     (__attribute__((address_space(3))) unsigned int*)(dst), 16, 0, 0)

// ---------------- cast Y*D weight matrix (U or fw) to bf16 ----------------
__global__ __launch_bounds__(256) void cast_w_k(const float* __restrict__ W, u16* __restrict__ W16) {
    int i = blockIdx.x * 256 + threadIdx.x;          // one float4 per thread
    float4 v = ((const float4*)W)[i];
    uint2 h;
    h.x = pkbf(v.x, v.y); h.y = pkbf(v.z, v.w);
    ((uint2*)W16)[i] = h;
}

// ---------------- cast x (B*L*D) to bf16, pure elementwise (no transpose needed) --------
__global__ __launch_bounds__(256) void cast_x_k(const float* __restrict__ x, u16* __restrict__ x16) {
    int i = blockIdx.x * 256 + threadIdx.x;          // one float4 per thread
    float4 v = ((const float4*)x)[i];
    uint2 h;
    h.x = pkbf(v.x, v.y); h.y = pkbf(v.z, v.w);
    ((uint2*)x16)[i] = h;
}

// ---------------- FUSED kernel: S=U.x^T and G=fw.x^T per tile, epilogue exp(S)*G -------
// y[b,r] = sum_l exp(att[r,l]) * G[r,l] / rowsum[r]   (summation order swapped — no att
// materialization, no second GEMM, no x-transpose).
// m-dim = l (x tile staged), n-dim = y (U16 and fw16 tiles staged). All three operands
// double-buffered via global_load_lds; ONE barrier per K-iter; K-loop unrolled by 2 with
// pointer bump (R7 lesson: full unroll blows I-cache; rolled-by-2 folds parity constants).
// Epilogue: e=exp(S), partial rowsum += e and ynum += e*G per y-row via 2 shfl + atomics.
__global__ __launch_bounds__(256) void fused_k(const u16* __restrict__ Xg, const u16* __restrict__ Ug,
                                               const u16* __restrict__ Wg,
                                               float* __restrict__ rowsum, float* __restrict__ ynum) {
    __shared__ u16 As[2 * 4096];      // x tile: 128 l-rows x 32 k (dbuf, 16 KB)
    __shared__ u16 Us[2 * 4096];      // U tile: 128 y-rows x 32 k
    __shared__ u16 Ws[2 * 4096];      // fw tile
    const int id = blockIdx.x;
    const int b = id & 7;             // batch pinned per XCD (%8 round-robin heuristic)
    const int r = id >> 3;
    const int nblk = r & 15;          // y-block; inner: 16 y-blocks share one staged x tile
    const int mblk = r >> 4;          // l-block
    const u16* A = Xg + (size_t)b * LL * DD;
    rowsum += (size_t)b * YY;
    ynum   += (size_t)b * YY;
    const int m0 = mblk * 128;        // l
    const int n0 = nblk * 128;        // y
    const int t = threadIdx.x;
    const int lane = t & 63;
    const int wave = t >> 6;
    const int wm = (wave >> 1) * 64;  // l-offset of wave
    const int wn = (wave & 1) * 64;   // y-offset of wave
    const int ln = lane & 15;
    const int qd = lane >> 4;
    const int swz = (qd ^ ((ln >> 1) & 3)) * 8;   // conflict-free ds_read_b128 swizzle

    const int kq0 = (t & 3) ^ ((t >> 3) & 3);
    const u16* Ab0 = A + (size_t)(m0 + (t >> 2)) * DD + kq0 * 8;
    const u16* Ab1 = A + (size_t)(m0 + (t >> 2) + 64) * DD + kq0 * 8;
    const u16* Ub0 = Ug + (size_t)(n0 + (t >> 2)) * DD + kq0 * 8;
    const u16* Ub1 = Ug + (size_t)(n0 + (t >> 2) + 64) * DD + kq0 * 8;
    const u16* Wb0 = Wg + (size_t)(n0 + (t >> 2)) * DD + kq0 * 8;
    const u16* Wb1 = Wg + (size_t)(n0 + (t >> 2) + 64) * DD + kq0 * 8;
    const int c0 = t * 8, c1 = (t + 256) * 8;

    // prologue: stage kt=0 into buf 0
    GLL(Ab0, As + c0); GLL(Ab1, As + c1);
    GLL(Ub0, Us + c0); GLL(Ub1, Us + c1);
    GLL(Wb0, Ws + c0); GLL(Wb1, Ws + c1);

    f32x4 aS[4][4] = {};
    f32x4 aG[4][4] = {};
    const int au = (wm + ln) * 32 + swz;
    const int bu = (wn + ln) * 32 + swz;

#define COMPUTE(pb)                                                                 \
    {                                                                               \
        bf16x8 af[4], bfU[4], bfW[4];                                               \
        _Pragma("unroll")                                                           \
        for (int i = 0; i < 4; ++i) {                                               \
            af[i]  = *(const bf16x8*)(As + (pb) + au + i * 512);                    \
            bfU[i] = *(const bf16x8*)(Us + (pb) + bu + i * 512);                    \
            bfW[i] = *(const bf16x8*)(Ws + (pb) + bu + i * 512);                    \
        }                                                                           \
        _Pragma("unroll")                                                           \
        for (int i = 0; i < 4; ++i)                                                 \
            _Pragma("unroll")                                                       \
            for (int j = 0; j < 4; ++j) {                                           \
                aS[i][j] = __builtin_amdgcn_mfma_f32_16x16x32_bf16(af[i], bfU[j], aS[i][j], 0, 0, 0); \
                aG[i][j] = __builtin_amdgcn_mfma_f32_16x16x32_bf16(af[i], bfW[j], aG[i][j], 0, 0, 0); \
            }                                                                       \
    }

    for (int kt2 = 0; kt2 < 12; ++kt2) {
        // phase 0: compute buf0 (tile 2*kt2), prefetch tile 2*kt2+1 into buf1 (+32 elems)
        __syncthreads();
        GLL(Ab0 + 32, As + 4096 + c0); GLL(Ab1 + 32, As + 4096 + c1);
        GLL(Ub0 + 32, Us + 4096 + c0); GLL(Ub1 + 32, Us + 4096 + c1);
        GLL(Wb0 + 32, Ws + 4096 + c0); GLL(Wb1 + 32, Ws + 4096 + c1);
        COMPUTE(0)
        // phase 1: compute buf1, prefetch tile 2*kt2+2 into buf0 (+64 elems)
        __syncthreads();
        if (kt2 < 11) {
            GLL(Ab0 + 64, As + c0); GLL(Ab1 + 64, As + c1);
            GLL(Ub0 + 64, Us + c0); GLL(Ub1 + 64, Us + c1);
            GLL(Wb0 + 64, Ws + c0); GLL(Wb1 + 64, Ws + c1);
        }
        COMPUTE(4096)
        Ab0 += 64; Ab1 += 64; Ub0 += 64; Ub1 += 64; Wb0 += 64; Wb1 += 64;
    }
#undef COMPUTE

    // epilogue: acc[i][j][rr] -> (y = n0+wn+j*16+ln, l = m0+wm+i*16+qd*4+rr)
    // rs = sum_l exp(S);  ys = sum_l exp(S)*G   over this wave's 64 l-values
    #pragma unroll
    for (int j = 0; j < 4; ++j) {
        const int y = n0 + wn + j * 16 + ln;
        float rs = 0.f, ys = 0.f;
        #pragma unroll
        for (int i = 0; i < 4; ++i) {
            #pragma unroll
            for (int rr = 0; rr < 4; ++rr) {
                float e = __expf(aS[i][j][rr]);
                rs += e;
                ys += e * aG[i][j][rr];
            }
        }
        rs += __shfl_xor(rs, 16, 64);  ys += __shfl_xor(ys, 16, 64);
        rs += __shfl_xor(rs, 32, 64);  ys += __shfl_xor(ys, 32, 64);
        if (qd == 0) {
            atomicAdd(&rowsum[y], rs);
            atomicAdd(&ynum[y], ys);
        }
    }
}

// -------- finalize: y = ynum/rowsum + bias (writeback), CE loss over y --------
__global__ __launch_bounds__(256) void ce_loss_k(const float* __restrict__ ynum,
                                                 const float* __restrict__ rowsum,
                                                 const float* __restrict__ fb,
                                                 const int* __restrict__ tgt,
                                                 float* __restrict__ out0,
                                                 float* __restrict__ yv) {
    __shared__ float part[8];
    const int t = threadIdx.x;
    const int wave = t >> 6, lane = t & 63;
    #pragma unroll
    for (int rep = 0; rep < 2; ++rep) {
        const int b = wave + rep * 4;
        const float* yn = ynum + b * YY;
        const float* rsm = rowsum + b * YY;
        float* row = yv + b * YY;
        const int tg = tgt[b];
        float v[32];
        float mx = -3.0e38f;
        #pragma unroll
        for (int i = 0; i < 32; ++i) {
            const int idx = lane + 64 * i;
            v[i] = yn[idx] / rsm[idx] + fb[idx];
            mx = fmaxf(mx, v[i]);
        }
        float tv = 0.f;
        #pragma unroll
        for (int i = 0; i < 32; ++i) {
            if (lane + 64 * i == tg) tv = v[i];
            row[lane + 64 * i] = v[i];          // write final y
        }
        for (int o = 32; o; o >>= 1) mx = fmaxf(mx, __shfl_down(mx, o, 64));
        mx = __shfl(mx, 0, 64);
        float s = 0.f;
        #pragma unroll
        for (int i = 0; i < 32; ++i) s += __expf(v[i] - mx);
        for (int o = 32; o; o >>= 1) { s += __shfl_down(s, o, 64); tv += __shfl_down(tv, o, 64); }
        if (lane == 0) part[b] = mx + logf(s) - tv;
    }
    __syncthreads();
    if (t == 0) {
        float tot = 0.f;
        #pragma unroll
        for (int i = 0; i < 8; ++i) tot += part[i];
        out0[0] = tot * 0.125f;
    }
}

extern "C" void kernel_launch(void* const* d_in, const int* in_sizes, int n_in,
                              void* d_out, int out_size, void* d_ws, size_t ws_size,
                              hipStream_t stream) {
    const float* x   = (const float*)d_in[0];   // (B,L,D)
    const float* Uw  = (const float*)d_in[1];   // (Y,D)
    const float* fw  = (const float*)d_in[2];   // (Y,D)
    const float* fb  = (const float*)d_in[3];   // (Y,)
    const int*   tgt = (const int*)d_in[4];     // (B,)
    float* out = (float*)d_out;                 // [loss, y(B*Y)]

    char* ws = (char*)d_ws;
    u16*  x16  = (u16*)(ws);                          // B*L*D bf16 = 50,331,648 B
    u16*  U16  = (u16*)(ws + 50331648);               // Y*D bf16   =  3,145,728 B
    u16*  fw16 = (u16*)(ws + 53477376);               // Y*D bf16   =  3,145,728 B
    float* rowsum = (float*)(ws + 56623104);          // B*Y fp32   =     65,536 B
    float* ynum   = (float*)(ws + 56688640);          // B*Y fp32   =     65,536 B

    hipMemsetAsync(rowsum, 0, 2 * (size_t)BB * YY * sizeof(float), stream);  // rowsum+ynum
    cast_w_k<<<1536, 256, 0, stream>>>(Uw, U16);
    cast_w_k<<<1536, 256, 0, stream>>>(fw, fw16);
    cast_x_k<<<(BB * LL * DD) / 1024, 256, 0, stream>>>(x, x16);

    // Fused S/G GEMM + exp + reductions: 32 l-blocks x 16 y-blocks x 8 b = 4096 blocks
    fused_k<<<(LL / 128) * (YY / 128) * BB, 256, 0, stream>>>(x16, U16, fw16, rowsum, ynum);

    ce_loss_k<<<1, 256, 0, stream>>>(ynum, rowsum, fb, tgt, out, out + 1);
}

// Round 9
// 414.102 us; speedup vs baseline: 1.4892x; 1.4892x over previous
//
#include <hip/hip_runtime.h>
#include <hip/hip_bf16.h>
#include <cstdint>

// Problem constants: B=8, L=4096, D=768, Y=2048
#define BB 8
#define LL 4096
#define DD 768
#define YY 2048

typedef unsigned short u16;
typedef __bf16 bf16x8 __attribute__((ext_vector_type(8)));
typedef __bf16 bf16x2 __attribute__((ext_vector_type(2)));
typedef float f32x4 __attribute__((ext_vector_type(4)));

__device__ __forceinline__ u16 f2bf(float f) {
    uint32_t u = __float_as_uint(f);
    u += 0x7fffu + ((u >> 16) & 1u);   // RNE
    return (u16)(u >> 16);
}

__device__ __forceinline__ uint32_t pkbf(float a, float b) {
#if __has_builtin(__builtin_amdgcn_cvt_pk_bf16_f32)
    bf16x2 p = __builtin_amdgcn_cvt_pk_bf16_f32(a, b);
    return __builtin_bit_cast(uint32_t, p);
#else
    return (uint32_t)f2bf(a) | ((uint32_t)f2bf(b) << 16);
#endif
}

#define GLL(src, dst) \
    __builtin_amdgcn_global_load_lds((const __attribute__((address_space(1))) unsigned int*)(src), \
                                     (__attribute__((address_space(3))) unsigned int*)(dst), 16, 0, 0)

// ---------------- cast Y*D weight matrix (U or fw) to bf16 ----------------
__global__ __launch_bounds__(256) void cast_w_k(const float* __restrict__ W, u16* __restrict__ W16) {
    int i = blockIdx.x * 256 + threadIdx.x;          // one float4 per thread
    float4 v = ((const float4*)W)[i];
    uint2 h;
    h.x = pkbf(v.x, v.y); h.y = pkbf(v.z, v.w);
    ((uint2*)W16)[i] = h;
}

// ---------------- cast x (B*L*D) to bf16, pure elementwise ----------------
__global__ __launch_bounds__(256) void cast_x_k(const float* __restrict__ x, u16* __restrict__ x16) {
    int i = blockIdx.x * 256 + threadIdx.x;          // one float4 per thread
    float4 v = ((const float4*)x)[i];
    uint2 h;
    h.x = pkbf(v.x, v.y); h.y = pkbf(v.z, v.w);
    ((uint2*)x16)[i] = h;
}

// ---------------- FUSED kernel: S=U.x^T and G=fw.x^T, epilogue sum exp(S), exp(S)*G ------
// y[b,r] = sum_l exp(att[r,l]) * G[r,l] / rowsum[r]   (summation order swapped: no att
// buffer, no second GEMM, no x transpose).
// R8 lesson: 128x128 fused tile -> 128 acc regs + 48 KB LDS -> 1 block/CU (Occ 11.6%).
// R9 fix: BM=128(l) x BN=64(y); per-wave 64x32 -> 64 acc regs; LDS 32 KB; lb(256,4)
// pins VGPR<=128 -> 4 blocks/CU. Same arithmetic intensity (A-tile feeds 2 MFMA streams).
__global__ __launch_bounds__(256, 4) void fused_k(const u16* __restrict__ Xg, const u16* __restrict__ Ug,
                                                  const u16* __restrict__ Wg,
                                                  float* __restrict__ rowsum, float* __restrict__ ynum) {
    __shared__ u16 As[2 * 4096];      // x tile: 128 l-rows x 32 k (dbuf, 16 KB)
    __shared__ u16 Us[2 * 2048];      // U tile: 64 y-rows x 32 k (dbuf, 8 KB)
    __shared__ u16 Ws[2 * 2048];      // fw tile (8 KB)
    const int id = blockIdx.x;
    const int b = id & 7;             // batch pinned per XCD (%8 round-robin heuristic)
    const int r = id >> 3;
    const int nblk = r & 31;          // y-block (64-wide); inner: 32 y-blocks share one x tile
    const int mblk = r >> 5;          // l-block
    const u16* A = Xg + (size_t)b * LL * DD;
    rowsum += (size_t)b * YY;
    ynum   += (size_t)b * YY;
    const int m0 = mblk * 128;        // l
    const int n0 = nblk * 64;         // y
    const int t = threadIdx.x;
    const int lane = t & 63;
    const int wave = t >> 6;
    const int wm = (wave >> 1) * 64;  // l-offset of wave
    const int wn = (wave & 1) * 32;   // y-offset of wave
    const int ln = lane & 15;
    const int qd = lane >> 4;
    const int swz = (qd ^ ((ln >> 1) & 3)) * 8;   // conflict-free ds_read_b128 swizzle

    const int kq0 = (t & 3) ^ ((t >> 3) & 3);
    const u16* Ab0 = A + (size_t)(m0 + (t >> 2)) * DD + kq0 * 8;       // rows 0..63
    const u16* Ab1 = A + (size_t)(m0 + (t >> 2) + 64) * DD + kq0 * 8;  // rows 64..127
    const u16* Ub0 = Ug + (size_t)(n0 + (t >> 2)) * DD + kq0 * 8;      // 64 rows, 1 GLL
    const u16* Wb0 = Wg + (size_t)(n0 + (t >> 2)) * DD + kq0 * 8;
    const int c0 = t * 8, c1 = (t + 256) * 8;

    // prologue: stage kt=0 into buf 0
    GLL(Ab0, As + c0); GLL(Ab1, As + c1);
    GLL(Ub0, Us + c0); GLL(Wb0, Ws + c0);

    f32x4 aS[4][2] = {};
    f32x4 aG[4][2] = {};
    const int au = (wm + ln) * 32 + swz;
    const int bu = (wn + ln) * 32 + swz;

#define COMPUTE(pa, pw)                                                             \
    {                                                                               \
        bf16x8 af[4], bfU[2], bfW[2];                                               \
        _Pragma("unroll")                                                           \
        for (int i = 0; i < 4; ++i)                                                 \
            af[i] = *(const bf16x8*)(As + (pa) + au + i * 512);                     \
        _Pragma("unroll")                                                           \
        for (int j = 0; j < 2; ++j) {                                               \
            bfU[j] = *(const bf16x8*)(Us + (pw) + bu + j * 512);                    \
            bfW[j] = *(const bf16x8*)(Ws + (pw) + bu + j * 512);                    \
        }                                                                           \
        _Pragma("unroll")                                                           \
        for (int i = 0; i < 4; ++i)                                                 \
            _Pragma("unroll")                                                       \
            for (int j = 0; j < 2; ++j) {                                           \
                aS[i][j] = __builtin_amdgcn_mfma_f32_16x16x32_bf16(af[i], bfU[j], aS[i][j], 0, 0, 0); \
                aG[i][j] = __builtin_amdgcn_mfma_f32_16x16x32_bf16(af[i], bfW[j], aG[i][j], 0, 0, 0); \
            }                                                                       \
    }

    for (int kt2 = 0; kt2 < 12; ++kt2) {
        // phase 0: compute buf0 (tile 2*kt2), prefetch tile 2*kt2+1 into buf1
        __syncthreads();
        GLL(Ab0 + 32, As + 4096 + c0); GLL(Ab1 + 32, As + 4096 + c1);
        GLL(Ub0 + 32, Us + 2048 + c0); GLL(Wb0 + 32, Ws + 2048 + c0);
        COMPUTE(0, 0)
        // phase 1: compute buf1, prefetch tile 2*kt2+2 into buf0
        __syncthreads();
        if (kt2 < 11) {
            GLL(Ab0 + 64, As + c0); GLL(Ab1 + 64, As + c1);
            GLL(Ub0 + 64, Us + c0); GLL(Wb0 + 64, Ws + c0);
        }
        COMPUTE(4096, 2048)
        Ab0 += 64; Ab1 += 64; Ub0 += 64; Wb0 += 64;
    }
#undef COMPUTE

    // epilogue: acc[i][j][rr] -> (y = n0+wn+j*16+ln, l = m0+wm+i*16+qd*4+rr)
    #pragma unroll
    for (int j = 0; j < 2; ++j) {
        const int y = n0 + wn + j * 16 + ln;
        float rs = 0.f, ys = 0.f;
        #pragma unroll
        for (int i = 0; i < 4; ++i) {
            #pragma unroll
            for (int rr = 0; rr < 4; ++rr) {
                float e = __expf(aS[i][j][rr]);
                rs += e;
                ys += e * aG[i][j][rr];
            }
        }
        rs += __shfl_xor(rs, 16, 64);  ys += __shfl_xor(ys, 16, 64);
        rs += __shfl_xor(rs, 32, 64);  ys += __shfl_xor(ys, 32, 64);
        if (qd == 0) {
            atomicAdd(&rowsum[y], rs);
            atomicAdd(&ynum[y], ys);
        }
    }
}

// -------- finalize: y = ynum/rowsum + bias (writeback), CE loss over y --------
__global__ __launch_bounds__(256) void ce_loss_k(const float* __restrict__ ynum,
                                                 const float* __restrict__ rowsum,
                                                 const float* __restrict__ fb,
                                                 const int* __restrict__ tgt,
                                                 float* __restrict__ out0,
                                                 float* __restrict__ yv) {
    __shared__ float part[8];
    const int t = threadIdx.x;
    const int wave = t >> 6, lane = t & 63;
    #pragma unroll
    for (int rep = 0; rep < 2; ++rep) {
        const int b = wave + rep * 4;
        const float* yn = ynum + b * YY;
        const float* rsm = rowsum + b * YY;
        float* row = yv + b * YY;
        const int tg = tgt[b];
        float v[32];
        float mx = -3.0e38f;
        #pragma unroll
        for (int i = 0; i < 32; ++i) {
            const int idx = lane + 64 * i;
            v[i] = yn[idx] / rsm[idx] + fb[idx];
            mx = fmaxf(mx, v[i]);
        }
        float tv = 0.f;
        #pragma unroll
        for (int i = 0; i < 32; ++i) {
            if (lane + 64 * i == tg) tv = v[i];
            row[lane + 64 * i] = v[i];          // write final y
        }
        for (int o = 32; o; o >>= 1) mx = fmaxf(mx, __shfl_down(mx, o, 64));
        mx = __shfl(mx, 0, 64);
        float s = 0.f;
        #pragma unroll
        for (int i = 0; i < 32; ++i) s += __expf(v[i] - mx);
        for (int o = 32; o; o >>= 1) { s += __shfl_down(s, o, 64); tv += __shfl_down(tv, o, 64); }
        if (lane == 0) part[b] = mx + logf(s) - tv;
    }
    __syncthreads();
    if (t == 0) {
        float tot = 0.f;
        #pragma unroll
        for (int i = 0; i < 8; ++i) tot += part[i];
        out0[0] = tot * 0.125f;
    }
}

extern "C" void kernel_launch(void* const* d_in, const int* in_sizes, int n_in,
                              void* d_out, int out_size, void* d_ws, size_t ws_size,
                              hipStream_t stream) {
    const float* x   = (const float*)d_in[0];   // (B,L,D)
    const float* Uw  = (const float*)d_in[1];   // (Y,D)
    const float* fw  = (const float*)d_in[2];   // (Y,D)
    const float* fb  = (const float*)d_in[3];   // (Y,)
    const int*   tgt = (const int*)d_in[4];     // (B,)
    float* out = (float*)d_out;                 // [loss, y(B*Y)]

    char* ws = (char*)d_ws;
    u16*  x16  = (u16*)(ws);                          // B*L*D bf16 = 50,331,648 B
    u16*  U16  = (u16*)(ws + 50331648);               // Y*D bf16   =  3,145,728 B
    u16*  fw16 = (u16*)(ws + 53477376);               // Y*D bf16   =  3,145,728 B
    float* rowsum = (float*)(ws + 56623104);          // B*Y fp32   =     65,536 B
    float* ynum   = (float*)(ws + 56688640);          // B*Y fp32   =     65,536 B

    hipMemsetAsync(rowsum, 0, 2 * (size_t)BB * YY * sizeof(float), stream);  // rowsum+ynum
    cast_w_k<<<1536, 256, 0, stream>>>(Uw, U16);
    cast_w_k<<<1536, 256, 0, stream>>>(fw, fw16);
    cast_x_k<<<(BB * LL * DD) / 1024, 256, 0, stream>>>(x, x16);

    // Fused S/G GEMM + exp + reductions: 32 l-blocks x 32 y-blocks x 8 b = 8192 blocks
    fused_k<<<(LL / 128) * (YY / 64) * BB, 256, 0, stream>>>(x16, U16, fw16, rowsum, ynum);

    ce_loss_k<<<1, 256, 0, stream>>>(ynum, rowsum, fb, tgt, out, out + 1);
}

// Round 10
// 403.964 us; speedup vs baseline: 1.5266x; 1.0251x over previous
//
#include <hip/hip_runtime.h>
#include <hip/hip_bf16.h>
#include <cstdint>

// Problem constants: B=8, L=4096, D=768, Y=2048
#define BB 8
#define LL 4096
#define DD 768
#define YY 2048

typedef unsigned short u16;
typedef __bf16 bf16x8 __attribute__((ext_vector_type(8)));
typedef __bf16 bf16x2 __attribute__((ext_vector_type(2)));
typedef float f32x4 __attribute__((ext_vector_type(4)));

__device__ __forceinline__ u16 f2bf(float f) {
    uint32_t u = __float_as_uint(f);
    u += 0x7fffu + ((u >> 16) & 1u);   // RNE
    return (u16)(u >> 16);
}

__device__ __forceinline__ uint32_t pkbf(float a, float b) {
#if __has_builtin(__builtin_amdgcn_cvt_pk_bf16_f32)
    bf16x2 p = __builtin_amdgcn_cvt_pk_bf16_f32(a, b);
    return __builtin_bit_cast(uint32_t, p);
#else
    return (uint32_t)f2bf(a) | ((uint32_t)f2bf(b) << 16);
#endif
}

#define GLL(src, dst) \
    __builtin_amdgcn_global_load_lds((const __attribute__((address_space(1))) unsigned int*)(src), \
                                     (__attribute__((address_space(3))) unsigned int*)(dst), 16, 0, 0)

// ---------------- cast Y*D weight matrix (U or fw) to bf16 ----------------
__global__ __launch_bounds__(256) void cast_w_k(const float* __restrict__ W, u16* __restrict__ W16) {
    int i = blockIdx.x * 256 + threadIdx.x;          // one float4 per thread
    float4 v = ((const float4*)W)[i];
    uint2 h;
    h.x = pkbf(v.x, v.y); h.y = pkbf(v.z, v.w);
    ((uint2*)W16)[i] = h;
}

// ---------------- cast x (B*L*D) to bf16, pure elementwise ----------------
__global__ __launch_bounds__(256) void cast_x_k(const float* __restrict__ x, u16* __restrict__ x16) {
    int i = blockIdx.x * 256 + threadIdx.x;          // one float4 per thread
    float4 v = ((const float4*)x)[i];
    uint2 h;
    h.x = pkbf(v.x, v.y); h.y = pkbf(v.z, v.w);
    ((uint2*)x16)[i] = h;
}

// ---------------- FUSED kernel: S=U.x^T and G=fw.x^T, epilogue sum exp(S), exp(S)*G ------
// y[b,r] = sum_l exp(att[r,l]) * G[r,l] / rowsum[r]   (summation order swapped: no att
// buffer, no second GEMM, no x transpose).
// R9: BM=128(l) x BN=64(y), 64 acc regs, 32 KB LDS, 4 blocks/CU -> 270 us.
// R10: block order for per-XCD L2 residency. R9's order re-fetched all of U16+fw16
// (6.3 MB > 4 MB L2) per l-block -> FETCH 256 MB, HBM-miss GLLs (~900 cyc) stall every
// barrier. New id mapping: b | yhalf | mblk | nblk16(inner): inner 16 y-blocks
// (U/fw-half = 3.2 MB, L2-RESIDENT) share one x-tile; x streamed once per yhalf.
__global__ __launch_bounds__(256, 4) void fused_k(const u16* __restrict__ Xg, const u16* __restrict__ Ug,
                                                  const u16* __restrict__ Wg,
                                                  float* __restrict__ rowsum, float* __restrict__ ynum) {
    __shared__ u16 As[2 * 4096];      // x tile: 128 l-rows x 32 k (dbuf, 16 KB)
    __shared__ u16 Us[2 * 2048];      // U tile: 64 y-rows x 32 k (dbuf, 8 KB)
    __shared__ u16 Ws[2 * 2048];      // fw tile (8 KB)
    const int id = blockIdx.x;
    const int b = id & 7;             // batch pinned per XCD (%8 round-robin heuristic)
    const int r = id >> 3;            // 0..1023
    const int yhalf = r >> 9;         // 0..1   (outer: U/fw half swapped once)
    const int q = r & 511;
    const int mblk = q >> 4;          // 0..31  (middle: x-tile advances, U/fw-half L2-hot)
    const int nblk = (yhalf << 4) + (q & 15);   // inner 16 y-blocks share one x-tile
    const u16* A = Xg + (size_t)b * LL * DD;
    rowsum += (size_t)b * YY;
    ynum   += (size_t)b * YY;
    const int m0 = mblk * 128;        // l
    const int n0 = nblk * 64;         // y
    const int t = threadIdx.x;
    const int lane = t & 63;
    const int wave = t >> 6;
    const int wm = (wave >> 1) * 64;  // l-offset of wave
    const int wn = (wave & 1) * 32;   // y-offset of wave
    const int ln = lane & 15;
    const int qd = lane >> 4;
    const int swz = (qd ^ ((ln >> 1) & 3)) * 8;   // conflict-free ds_read_b128 swizzle

    const int kq0 = (t & 3) ^ ((t >> 3) & 3);
    const u16* Ab0 = A + (size_t)(m0 + (t >> 2)) * DD + kq0 * 8;       // rows 0..63
    const u16* Ab1 = A + (size_t)(m0 + (t >> 2) + 64) * DD + kq0 * 8;  // rows 64..127
    const u16* Ub0 = Ug + (size_t)(n0 + (t >> 2)) * DD + kq0 * 8;      // 64 rows, 1 GLL
    const u16* Wb0 = Wg + (size_t)(n0 + (t >> 2)) * DD + kq0 * 8;
    const int c0 = t * 8, c1 = (t + 256) * 8;

    // prologue: stage kt=0 into buf 0
    GLL(Ab0, As + c0); GLL(Ab1, As + c1);
    GLL(Ub0, Us + c0); GLL(Wb0, Ws + c0);

    f32x4 aS[4][2] = {};
    f32x4 aG[4][2] = {};
    const int au = (wm + ln) * 32 + swz;
    const int bu = (wn + ln) * 32 + swz;

#define COMPUTE(pa, pw)                                                             \
    {                                                                               \
        bf16x8 af[4], bfU[2], bfW[2];                                               \
        _Pragma("unroll")                                                           \
        for (int i = 0; i < 4; ++i)                                                 \
            af[i] = *(const bf16x8*)(As + (pa) + au + i * 512);                     \
        _Pragma("unroll")                                                           \
        for (int j = 0; j < 2; ++j) {                                               \
            bfU[j] = *(const bf16x8*)(Us + (pw) + bu + j * 512);                    \
            bfW[j] = *(const bf16x8*)(Ws + (pw) + bu + j * 512);                    \
        }                                                                           \
        _Pragma("unroll")                                                           \
        for (int i = 0; i < 4; ++i)                                                 \
            _Pragma("unroll")                                                       \
            for (int j = 0; j < 2; ++j) {                                           \
                aS[i][j] = __builtin_amdgcn_mfma_f32_16x16x32_bf16(af[i], bfU[j], aS[i][j], 0, 0, 0); \
                aG[i][j] = __builtin_amdgcn_mfma_f32_16x16x32_bf16(af[i], bfW[j], aG[i][j], 0, 0, 0); \
            }                                                                       \
    }

    for (int kt2 = 0; kt2 < 12; ++kt2) {
        // phase 0: compute buf0 (tile 2*kt2), prefetch tile 2*kt2+1 into buf1
        __syncthreads();
        GLL(Ab0 + 32, As + 4096 + c0); GLL(Ab1 + 32, As + 4096 + c1);
        GLL(Ub0 + 32, Us + 2048 + c0); GLL(Wb0 + 32, Ws + 2048 + c0);
        COMPUTE(0, 0)
        // phase 1: compute buf1, prefetch tile 2*kt2+2 into buf0
        __syncthreads();
        if (kt2 < 11) {
            GLL(Ab0 + 64, As + c0); GLL(Ab1 + 64, As + c1);
            GLL(Ub0 + 64, Us + c0); GLL(Wb0 + 64, Ws + c0);
        }
        COMPUTE(4096, 2048)
        Ab0 += 64; Ab1 += 64; Ub0 += 64; Wb0 += 64;
    }
#undef COMPUTE

    // epilogue: acc[i][j][rr] -> (y = n0+wn+j*16+ln, l = m0+wm+i*16+qd*4+rr)
    #pragma unroll
    for (int j = 0; j < 2; ++j) {
        const int y = n0 + wn + j * 16 + ln;
        float rs = 0.f, ys = 0.f;
        #pragma unroll
        for (int i = 0; i < 4; ++i) {
            #pragma unroll
            for (int rr = 0; rr < 4; ++rr) {
                float e = __expf(aS[i][j][rr]);
                rs += e;
                ys += e * aG[i][j][rr];
            }
        }
        rs += __shfl_xor(rs, 16, 64);  ys += __shfl_xor(ys, 16, 64);
        rs += __shfl_xor(rs, 32, 64);  ys += __shfl_xor(ys, 32, 64);
        if (qd == 0) {
            atomicAdd(&rowsum[y], rs);
            atomicAdd(&ynum[y], ys);
        }
    }
}

// -------- finalize: y = ynum/rowsum + bias (writeback), CE loss over y --------
__global__ __launch_bounds__(256) void ce_loss_k(const float* __restrict__ ynum,
                                                 const float* __restrict__ rowsum,
                                                 const float* __restrict__ fb,
                                                 const int* __restrict__ tgt,
                                                 float* __restrict__ out0,
                                                 float* __restrict__ yv) {
    __shared__ float part[8];
    const int t = threadIdx.x;
    const int wave = t >> 6, lane = t & 63;
    #pragma unroll
    for (int rep = 0; rep < 2; ++rep) {
        const int b = wave + rep * 4;
        const float* yn = ynum + b * YY;
        const float* rsm = rowsum + b * YY;
        float* row = yv + b * YY;
        const int tg = tgt[b];
        float v[32];
        float mx = -3.0e38f;
        #pragma unroll
        for (int i = 0; i < 32; ++i) {
            const int idx = lane + 64 * i;
            v[i] = yn[idx] / rsm[idx] + fb[idx];
            mx = fmaxf(mx, v[i]);
        }
        float tv = 0.f;
        #pragma unroll
        for (int i = 0; i < 32; ++i) {
            if (lane + 64 * i == tg) tv = v[i];
            row[lane + 64 * i] = v[i];          // write final y
        }
        for (int o = 32; o; o >>= 1) mx = fmaxf(mx, __shfl_down(mx, o, 64));
        mx = __shfl(mx, 0, 64);
        float s = 0.f;
        #pragma unroll
        for (int i = 0; i < 32; ++i) s += __expf(v[i] - mx);
        for (int o = 32; o; o >>= 1) { s += __shfl_down(s, o, 64); tv += __shfl_down(tv, o, 64); }
        if (lane == 0) part[b] = mx + logf(s) - tv;
    }
    __syncthreads();
    if (t == 0) {
        float tot = 0.f;
        #pragma unroll
        for (int i = 0; i < 8; ++i) tot += part[i];
        out0[0] = tot * 0.125f;
    }
}

extern "C" void kernel_launch(void* const* d_in, const int* in_sizes, int n_in,
                              void* d_out, int out_size, void* d_ws, size_t ws_size,
                              hipStream_t stream) {
    const float* x   = (const float*)d_in[0];   // (B,L,D)
    const float* Uw  = (const float*)d_in[1];   // (Y,D)
    const float* fw  = (const float*)d_in[2];   // (Y,D)
    const float* fb  = (const float*)d_in[3];   // (Y,)
    const int*   tgt = (const int*)d_in[4];     // (B,)
    float* out = (float*)d_out;                 // [loss, y(B*Y)]

    char* ws = (char*)d_ws;
    u16*  x16  = (u16*)(ws);                          // B*L*D bf16 = 50,331,648 B
    u16*  U16  = (u16*)(ws + 50331648);               // Y*D bf16   =  3,145,728 B
    u16*  fw16 = (u16*)(ws + 53477376);               // Y*D bf16   =  3,145,728 B
    float* rowsum = (float*)(ws + 56623104);          // B*Y fp32   =     65,536 B
    float* ynum   = (float*)(ws + 56688640);          // B*Y fp32   =     65,536 B

    hipMemsetAsync(rowsum, 0, 2 * (size_t)BB * YY * sizeof(float), stream);  // rowsum+ynum
    cast_w_k<<<1536, 256, 0, stream>>>(Uw, U16);
    cast_w_k<<<1536, 256, 0, stream>>>(fw, fw16);
    cast_x_k<<<(BB * LL * DD) / 1024, 256, 0, stream>>>(x, x16);

    // Fused S/G GEMM + exp + reductions: 8192 blocks, L2-resident-weights order
    fused_k<<<(LL / 128) * (YY / 64) * BB, 256, 0, stream>>>(x16, U16, fw16, rowsum, ynum);

    ce_loss_k<<<1, 256, 0, stream>>>(ynum, rowsum, fb, tgt, out, out + 1);
}